// Round 18
// baseline (40.629 us; speedup 1.0000x reference)
//
#include <hip/hip_runtime.h>
#include <hip/hip_bf16.h>

typedef float f32x4 __attribute__((ext_vector_type(4)));
typedef _Float16 f16x2 __attribute__((ext_vector_type(2)));
typedef _Float16 f16x8 __attribute__((ext_vector_type(8)));

#define CC   64
#define HID  256
#define NOUT 64
#define HOUT 384
#define MAXCELL 16
// LDS: cells[16][512] @0 | lds_a[16][160] @8192 | uv @10752 | w2 @11776
#define ALDS 8192
#define UVB2 10752
#define W2B  11776
#define SMEMB (W2B + 32768)        // 44544 B -> 3 blocks/CU (24 waves)

// ---- k_prep: w2 -> W2F frags, w1[0:64] -> W1F frags, w1[64:66] -> UVH f16
__global__ __launch_bounds__(256) void k_prep(const float* __restrict__ w1,
                                              const float* __restrict__ w2,
                                              _Float16* __restrict__ W2F,
                                              _Float16* __restrict__ W1F,
                                              _Float16* __restrict__ UVH) {
    int idx = blockIdx.x * 256 + threadIdx.x;
    if (idx < 16384) {
        int f = idx, e = f & 7, l = (f >> 3) & 63, grp = f >> 9;
        int ks = grp >> 2, ng = grp & 3;
        int k = ks * 32 + ((l >> 4) << 3) + e;
        int n = (ng << 4) + (l & 15);
        W2F[f] = (_Float16)w2[k * NOUT + n];
    } else if (idx < 32768) {
        int f = idx - 16384, e = f & 7, l = (f >> 3) & 63, grp = f >> 9;
        int ks = grp >> 4, ng = grp & 15;
        int k = ks * 32 + ((l >> 4) << 3) + e;
        int n = (ng << 4) + (l & 15);
        W1F[f] = (_Float16)w1[k * HID + n];
    } else if (idx < 32768 + 512) {
        int f = idx - 32768;
        UVH[f] = (_Float16)w1[(CC + (f >> 8)) * HID + (f & 255)];
    }
}

// ---- main (fused, strip-split): block = 8 waves, tile 16x16 px.
// Prologue: res->lds_a, w2->LDS, uv->LDS; G_local via MFMA.
// Pass A computes+stores strip A (w2 from GLOBAL: loads precede stores, safe).
// Pass B computes strip B from LDS ONLY (zero vmcnt) -> A-stores drain under it.
__global__ __launch_bounds__(512, 2) void k_main(const float* __restrict__ res,
                                                 const _Float16* __restrict__ W1F,
                                                 const float* __restrict__ b1,
                                                 const _Float16* __restrict__ W2F,
                                                 const _Float16* __restrict__ UVH,
                                                 const float* __restrict__ b2,
                                                 float* __restrict__ out) {
    const int jt = blockIdx.x;        // 0..23
    const int it = blockIdx.y;        // 0..23
    const int b  = blockIdx.z;        // 0..1
    const int tid = threadIdx.x;
    const int wv = tid >> 6, l = tid & 63;
    const int lhi = l >> 4, dj = l & 15;
    const int i0 = it * 16, j0 = jt * 16;

    __shared__ char smem[SMEMB];

    // ---- integer staged-cell bounds
    const int r0 = i0 / 6;
    const int i15 = i0 + 15, ci15 = i15 / 6;
    const int r1 = min(ci15 + ((i15 - 6 * ci15) == 5 ? 1 : 0), 63);
    const int c0 = j0 / 6;
    const int j15 = j0 + 15, cj15 = j15 / 6;
    const int c1 = min(cj15 + ((j15 - 6 * cj15) == 5 ? 1 : 0), 63);
    const int ncc = c1 - c0 + 1;              // 3 or 4
    const int ncell = (r1 - r0 + 1) * ncc;    // 9..16

    // ---- prologue A: res slice -> lds_a (f32->f16 transpose); w2 + uv -> LDS
#pragma unroll
    for (int t = 0; t < 2; ++t) {
        int idx = t * 512 + tid;              // 0..1023
        int c = idx >> 4, cl = idx & 15;
        if (cl < ncell) {
            int cr = (ncc == 4) ? (cl >> 2) : ((cl * 11) >> 5);
            int cc = cl - cr * ncc;
            float v = res[((b * CC + c) << 12) + ((r0 + cr) << 6) + (c0 + cc)];
            *(_Float16*)(smem + ALDS + cl * 160 + c * 2) = (_Float16)v;
        }
    }
    {
        const f32x4* w2g = (const f32x4*)W2F;
#pragma unroll
        for (int t = 0; t < 4; ++t)
            *(f32x4*)(smem + W2B + ((t * 512 + tid) << 4)) = w2g[t * 512 + tid];
    }
    if (tid < 64)
        *(f32x4*)(smem + UVB2 + (tid << 4)) = *(const f32x4*)(UVH + (tid << 3));
    float bbv[4];
#pragma unroll
    for (int ng = 0; ng < 4; ++ng) bbv[ng] = b2[(ng << 4) + dj];
    __syncthreads();

    // ---- prologue B: G_local[cell][n] via MFMA; wave handles n-groups q0,q0+1
    {
        const int q0 = wv << 1;
        f32x4 accg[2];
#pragma unroll
        for (int q = 0; q < 2; ++q) {
            float bb = b1[(q0 + q) * 16 + dj];
            accg[q] = (f32x4){bb, bb, bb, bb};
        }
#pragma unroll
        for (int ks2 = 0; ks2 < 2; ++ks2) {
            f16x8 afr = *(const f16x8*)(smem + ALDS + dj * 160 + ks2 * 64 + lhi * 16);
#pragma unroll
            for (int q = 0; q < 2; ++q) {
                f16x8 bfr = *(const f16x8*)(W1F + (((ks2 * 16 + q0 + q) * 64 + l) << 3));
                accg[q] = __builtin_amdgcn_mfma_f32_16x16x32_f16(afr, bfr, accg[q], 0, 0, 0);
            }
        }
#pragma unroll
        for (int q = 0; q < 2; ++q) {
            const int n = (q0 + q) * 16 + dj;
#pragma unroll
            for (int r = 0; r < 4; ++r) {
                const int cell = (lhi << 2) + r;
                *(_Float16*)(smem + (cell << 9) + n * 2) = (_Float16)accg[q][r];
            }
        }
    }
    __syncthreads();

    // ---- x setup (per lane)
    const int j = j0 + dj;
    const int cj = j / 6, pj = j - 6 * cj;
    const bool xs = (pj == 5) && (cj < 63);
    const float rx0 = (float)(2 * pj - 5) * (1.f / 6.f);
    const float rx1 = xs ? rx0 - 2.f : rx0;

    // ---- y setup
    const int ia = i0 + (wv << 1);
    const int cia = ia / 6, pia = ia - 6 * cia;
    const float ryA = (float)(2 * pia - 5) * (1.f / 6.f);
    const float ryB = ryA + (1.f / 3.f);
    const bool ysB = (pia == 4) && (cia < 63);
    const float ryB1 = ysB ? ryB - 2.f : ryB;

    const float aA0 = fabsf(ryA * rx0) + 1e-9f;
    const float aA1 = fabsf(ryA * rx1) + 1e-9f;
    const float invA = 1.f / (aA0 + aA1);
    const float W00A = xs ? aA1 * invA : 1.f;
    const float W01A = xs ? aA0 * invA : 0.f;
    const float aB0 = fabsf(ryB * rx0) + 1e-9f;
    const float aB1 = fabsf(ryB * rx1) + 1e-9f;
    const float aB2 = fabsf(ryB1 * rx0) + 1e-9f;
    const float aB3 = fabsf(ryB1 * rx1) + 1e-9f;
    const float invB = 1.f / (aB0 + aB1 + aB2 + aB3);
    float W00B = aB3, W01B = 0.f, W10B = 0.f, W11B = 0.f;
    if (xs) W01B += aB2; else W00B += aB2;
    if (ysB) W10B += aB1; else W00B += aB1;
    if (ysB && xs) W11B += aB0;
    else if (ysB)  W10B += aB0;
    else if (xs)   W01B += aB0;
    else           W00B += aB0;
    W00B *= invB; W01B *= invB; W10B *= invB; W11B *= invB;

#define DUP2(x) (f16x2){(_Float16)(x), (_Float16)(x)}
    const f16x2 ryAh = DUP2(ryA), ryBh = DUP2(ryB), ryB1h = DUP2(ryB1);
    const f16x2 rx0h = DUP2(rx0), rx1h = DUP2(rx1);
    const f16x2 W00Ah = DUP2(W00A), W01Ah = DUP2(W01A);
    const f16x2 W00Bh = DUP2(W00B), W01Bh = DUP2(W01B);
    const f16x2 W10h = DUP2(W10B), W11h = DUP2(W11B);
    const f16x2 zeroh = DUP2(0.f);

    const int lo16 = lhi << 4;
    const int rA = cia - r0;
    const int cm = cj - c0, cp = cm + (xs ? 1 : 0);
    const char* cell00 = smem + ((rA * ncc + cm) << 9) + lo16;
    const char* cell01 = smem + ((rA * ncc + cp) << 9) + lo16;
    const char* cell10 = cell00 + (ncc << 9);
    const char* cell11 = cell01 + (ncc << 9);
    const char* uvp = smem + UVB2 + lo16;
    const f16x8* w2g = (const f16x8*)W2F + l;               // global (pass A)
    const f16x8* w2s = (const f16x8*)(smem + W2B) + l;      // LDS (pass B)

    // ================= PASS A: strip A compute + store =================
    {
        f32x4 accA[4];
#pragma unroll
        for (int ng = 0; ng < 4; ++ng) accA[ng] = (f32x4){0.f, 0.f, 0.f, 0.f};
#pragma unroll
        for (int ks = 0; ks < 8; ++ks) {
            const int ko = ks * 64;
            f16x8 bfr[4];
#pragma unroll
            for (int ng = 0; ng < 4; ++ng) bfr[ng] = w2g[(ks * 4 + ng) * 64];
            f16x8 uraw = *(const f16x8*)(uvp + ko);
            f16x8 vraw = *(const f16x8*)(uvp + 512 + ko);
            const f16x2* uu = (const f16x2*)&uraw;
            const f16x2* vv = (const f16x2*)&vraw;
            f16x8 gv00 = *(const f16x8*)(cell00 + ko);
            f16x8 gv01 = *(const f16x8*)(cell01 + ko);
            const f16x2* g00 = (const f16x2*)&gv00;
            const f16x2* g01 = (const f16x2*)&gv01;
            union { f16x2 h2[4]; f16x8 v8; } HA;
#pragma unroll
            for (int e = 0; e < 4; ++e) {
                f16x2 t00 = g00[e] + ryAh * uu[e] + rx0h * vv[e];
                f16x2 t01 = g01[e] + ryAh * uu[e] + rx1h * vv[e];
                t00 = __builtin_elementwise_max(t00, zeroh);
                t01 = __builtin_elementwise_max(t01, zeroh);
                HA.h2[e] = W00Ah * t00 + W01Ah * t01;
            }
#pragma unroll
            for (int ng = 0; ng < 4; ++ng)
                accA[ng] = __builtin_amdgcn_mfma_f32_16x16x32_f16(HA.v8, bfr[ng], accA[ng], 0, 0, 0);
        }
        // store strip A now; drains during pass B (pass B has no vmcnt ops)
#pragma unroll
        for (int ng = 0; ng < 4; ++ng) {
            const int o = (ng << 4) + dj;
            f32x4 ov;
#pragma unroll
            for (int r = 0; r < 4; ++r) ov[r] = accA[ng][r] + bbv[ng];
            *(f32x4*)(out + (((size_t)b * NOUT + o) * HOUT + ia) * HOUT + j0 + (lhi << 2)) = ov;
        }
        __builtin_amdgcn_sched_barrier(0);   // pin A-stores before pass B
    }

    // ================= PASS B: strip B compute (LDS-only) + store =================
    {
        f32x4 accB[4];
#pragma unroll
        for (int ng = 0; ng < 4; ++ng) accB[ng] = (f32x4){0.f, 0.f, 0.f, 0.f};
#pragma unroll
        for (int ks = 0; ks < 8; ++ks) {
            const int ko = ks * 64;
            f16x8 bfr[4];
#pragma unroll
            for (int ng = 0; ng < 4; ++ng) bfr[ng] = w2s[(ks * 4 + ng) * 64];
            f16x8 uraw = *(const f16x8*)(uvp + ko);
            f16x8 vraw = *(const f16x8*)(uvp + 512 + ko);
            const f16x2* uu = (const f16x2*)&uraw;
            const f16x2* vv = (const f16x2*)&vraw;
            f16x8 gv00 = *(const f16x8*)(cell00 + ko);
            f16x8 gv01 = *(const f16x8*)(cell01 + ko);
            const f16x2* g00 = (const f16x2*)&gv00;
            const f16x2* g01 = (const f16x2*)&gv01;
            union { f16x2 h2[4]; f16x8 v8; } HB;
#pragma unroll
            for (int e = 0; e < 4; ++e) {
                f16x2 t00B = g00[e] + ryBh * uu[e] + rx0h * vv[e];
                f16x2 t01B = g01[e] + ryBh * uu[e] + rx1h * vv[e];
                t00B = __builtin_elementwise_max(t00B, zeroh);
                t01B = __builtin_elementwise_max(t01B, zeroh);
                HB.h2[e] = W00Bh * t00B + W01Bh * t01B;
            }
            if (ysB) {                                   // wave-uniform
                f16x8 gv10 = *(const f16x8*)(cell10 + ko);
                f16x8 gv11 = *(const f16x8*)(cell11 + ko);
                const f16x2* g10 = (const f16x2*)&gv10;
                const f16x2* g11 = (const f16x2*)&gv11;
#pragma unroll
                for (int e = 0; e < 4; ++e) {
                    f16x2 t10 = g10[e] + ryB1h * uu[e] + rx0h * vv[e];
                    f16x2 t11 = g11[e] + ryB1h * uu[e] + rx1h * vv[e];
                    HB.h2[e] += W10h * __builtin_elementwise_max(t10, zeroh);
                    HB.h2[e] += W11h * __builtin_elementwise_max(t11, zeroh);
                }
            }
#pragma unroll
            for (int ng = 0; ng < 4; ++ng)
                accB[ng] = __builtin_amdgcn_mfma_f32_16x16x32_f16(HB.v8, bfr[ng], accB[ng], 0, 0, 0);
        }
#pragma unroll
        for (int ng = 0; ng < 4; ++ng) {
            const int o = (ng << 4) + dj;
            f32x4 ov;
#pragma unroll
            for (int r = 0; r < 4; ++r) ov[r] = accB[ng][r] + bbv[ng];
            *(f32x4*)(out + (((size_t)b * NOUT + o) * HOUT + (ia + 1)) * HOUT + j0 + (lhi << 2)) = ov;
        }
    }
}

extern "C" void kernel_launch(void* const* d_in, const int* in_sizes, int n_in,
                              void* d_out, int out_size, void* d_ws, size_t ws_size,
                              hipStream_t stream) {
    const float* res = (const float*)d_in[0];
    const float* w1  = (const float*)d_in[1];
    const float* b1  = (const float*)d_in[2];
    const float* w2  = (const float*)d_in[3];
    const float* b2  = (const float*)d_in[4];
    float* out = (float*)d_out;

    char* ws = (char*)d_ws;
    _Float16* W2F = (_Float16*)(ws + (size_t)(8u << 20));       // 32 KB
    _Float16* W1F = (_Float16*)(ws + (size_t)(8u << 20) + 65536);
    _Float16* UVH = (_Float16*)(ws + (size_t)(8u << 20) + 131072);

    k_prep<<<130, 256, 0, stream>>>(w1, w2, W2F, W1F, UVH);
    k_main<<<dim3(24, 24, 2), 512, 0, stream>>>(res, W1F, b1, W2F, UVH, b2, out);
}